// Round 1
// 1498.430 us; speedup vs baseline: 1.2372x; 1.2372x over previous
//
#include <hip/hip_runtime.h>
#include <math.h>

typedef unsigned short u16;
typedef unsigned int u32;
typedef __bf16 bf16x8 __attribute__((ext_vector_type(8)));
typedef float f32x4 __attribute__((ext_vector_type(4)));

#define B_ 2
#define S_ 2048
#define H_ 4096
#define NH_ 32
#define NKV_ 8
#define HD_ 128
#define SCALE 0.08838834764831845f
#define MASK_NEG -30000.0f   // exp(-30000 - m) flushes to exactly 0.0f, same as np ref
#define M_INIT  -1.0e30f     // finite "minus infinity": exp(-1e30 - m) == 0.0f, no inf math

static __device__ __forceinline__ u16 f2bf(float f) {
  union { float f; u32 u; } v; v.f = f;
  u32 u = v.u;
  u += ((u >> 16) & 1u) + 0x7FFFu;   // round-to-nearest-even
  return (u16)(u >> 16);
}
static __device__ __forceinline__ float bf2f(u16 h) {
  union { u32 u; float f; } v; v.u = ((u32)h) << 16;
  return v.f;
}

// Load 8 contiguous elements starting at element offset `off`.
// F32 != 0: source is float32, convert to 8 bf16 (RTNE).  F32 == 0: source bf16.
template<int F32>
static __device__ __forceinline__ int4 ld8(const void* __restrict__ base, size_t off) {
  if (F32) {
    const float* p = (const float*)base + off;
    const float4 x0 = *(const float4*)p;
    const float4 x1 = *(const float4*)(p + 4);
    union { u16 h[8]; int4 v; } u;
    u.h[0] = f2bf(x0.x); u.h[1] = f2bf(x0.y); u.h[2] = f2bf(x0.z); u.h[3] = f2bf(x0.w);
    u.h[4] = f2bf(x1.x); u.h[5] = f2bf(x1.y); u.h[6] = f2bf(x1.z); u.h[7] = f2bf(x1.w);
    return u.v;
  }
  return *(const int4*)((const u16*)base + off);
}

// ---------------------------------------------------------------------------
// FALLBACK GEMM (only used if workspace is too small for the bf16 scratch):
// C[m][n] = sum_k A[m][k] * Bw[n][k], fp32->bf16 inline during LDS staging.
// ---------------------------------------------------------------------------
#define BK 32
#define LDA 40   // padded LDS stride for fallback path

template<int AF32, int BF32, int OUTF32>
__global__ __launch_bounds__(256) void gemm_bt(const void* __restrict__ A,
                                               const void* __restrict__ Bw,
                                               void* __restrict__ C,
                                               int M, int N, int K) {
  __shared__ u16 As[128 * LDA];
  __shared__ u16 Bs[128 * LDA];
  const int tid  = threadIdx.x;
  const int wave = tid >> 6;
  const int lane = tid & 63;
  const int quad = lane >> 4;
  const int l16  = lane & 15;
  const int wr = wave >> 1, wc = wave & 1;
  const int m0 = blockIdx.y * 128, n0 = blockIdx.x * 128;
  const int srow = tid >> 2;          // 0..63
  const int scol = (tid & 3) << 3;    // 0,8,16,24

  f32x4 acc[4][4];
  const f32x4 fz = {0.f, 0.f, 0.f, 0.f};
  for (int i = 0; i < 4; ++i)
    for (int j = 0; j < 4; ++j) acc[i][j] = fz;

  const size_t ao0 = (size_t)(m0 + srow)      * K + scol;
  const size_t ao1 = (size_t)(m0 + srow + 64) * K + scol;
  const size_t bo0 = (size_t)(n0 + srow)      * K + scol;
  const size_t bo1 = (size_t)(n0 + srow + 64) * K + scol;

  for (int k0 = 0; k0 < K; k0 += BK) {
    int4 a0 = ld8<AF32>(A,  ao0 + k0);
    int4 a1 = ld8<AF32>(A,  ao1 + k0);
    int4 b0 = ld8<BF32>(Bw, bo0 + k0);
    int4 b1 = ld8<BF32>(Bw, bo1 + k0);
    __syncthreads();
    *(int4*)&As[srow * LDA + scol]        = a0;
    *(int4*)&As[(srow + 64) * LDA + scol] = a1;
    *(int4*)&Bs[srow * LDA + scol]        = b0;
    *(int4*)&Bs[(srow + 64) * LDA + scol] = b1;
    __syncthreads();
    bf16x8 af[4], bfr[4];
#pragma unroll
    for (int mt = 0; mt < 4; ++mt)
      af[mt] = *(const bf16x8*)&As[(wr * 64 + mt * 16 + l16) * LDA + quad * 8];
#pragma unroll
    for (int nt = 0; nt < 4; ++nt)
      bfr[nt] = *(const bf16x8*)&Bs[(wc * 64 + nt * 16 + l16) * LDA + quad * 8];
#pragma unroll
    for (int mt = 0; mt < 4; ++mt)
#pragma unroll
      for (int nt = 0; nt < 4; ++nt)
        acc[mt][nt] = __builtin_amdgcn_mfma_f32_16x16x32_bf16(af[mt], bfr[nt],
                                                              acc[mt][nt], 0, 0, 0);
  }
#pragma unroll
  for (int mt = 0; mt < 4; ++mt)
#pragma unroll
    for (int nt = 0; nt < 4; ++nt) {
      int row = m0 + wr * 64 + mt * 16 + quad * 4;
      int col = n0 + wc * 64 + nt * 16 + l16;
      if (OUTF32) {
        float* cp = (float*)C + (size_t)row * N + col;
#pragma unroll
        for (int r = 0; r < 4; ++r)
          cp[(size_t)r * N] = acc[mt][nt][r];
      } else {
        u16* cp = (u16*)C + (size_t)row * N + col;
#pragma unroll
        for (int r = 0; r < 4; ++r)
          cp[(size_t)r * N] = f2bf(acc[mt][nt][r]);
      }
    }
}

// ---------------------------------------------------------------------------
// fp32 -> bf16 (RTNE) elementwise. One float4 read (16B/lane, coalesced),
// one uint2 write (8B/lane, coalesced) per thread. n4 = n_elems / 4.
// ---------------------------------------------------------------------------
__global__ __launch_bounds__(256) void cvt_bf16(const float* __restrict__ in,
                                                u16* __restrict__ out, u32 n4) {
  u32 i = blockIdx.x * 256u + threadIdx.x;
  if (i >= n4) return;
  const float4 x = ((const float4*)in)[i];
  u32 lo = (u32)f2bf(x.x) | ((u32)f2bf(x.y) << 16);
  u32 hi = (u32)f2bf(x.z) | ((u32)f2bf(x.w) << 16);
  ((uint2*)out)[i] = make_uint2(lo, hi);
}

// ---------------------------------------------------------------------------
// PRIMARY GEMM (m97 structure): both operands bf16 K-major in global memory,
// staged via global_load_lds width=16 into LINEAR LDS (no padding — the DMA
// writes wave-uniform-base + lane*16). 128x128 tile, BK=32, 4 waves (2x2),
// 4x4 MFMA 16x16x32 per wave.
// Tile staging: A tile = 128 rows x 32 cols bf16 = 8 KB = 512 x 16B chunks.
// chunk c -> row c>>2, elem ((c&3)*8). Thread tid covers chunks tid and
// tid+256 (rows r and r+64, same in-row offset) => LDS is exactly row-major
// [128][32] and fragment reads use LDA=32.
// ---------------------------------------------------------------------------
#define GLOAD16(gp, lp)                                            \
  __builtin_amdgcn_global_load_lds(                                \
      (__attribute__((address_space(1))) void*)(gp),               \
      (__attribute__((address_space(3))) void*)(lp), 16, 0, 0)

template<int OUTF32>
__global__ __launch_bounds__(256) void gemm_lds(const u16* __restrict__ A,
                                                const u16* __restrict__ Bw,
                                                void* __restrict__ C,
                                                int M, int N, int K) {
  __shared__ u16 As[128 * 32];
  __shared__ u16 Bs[128 * 32];
  const int tid  = threadIdx.x;
  const int wave = tid >> 6;
  const int lane = tid & 63;
  const int quad = lane >> 4;
  const int l16  = lane & 15;
  const int wr = wave >> 1, wc = wave & 1;
  const int m0 = blockIdx.y * 128, n0 = blockIdx.x * 128;

  // per-lane global source addresses (chunk tid and chunk tid+256)
  const int r0 = tid >> 2;            // 0..63
  const int e0 = (tid & 3) << 3;      // 0,8,16,24 elems within the 32-wide row
  const u16* a0 = A  + (size_t)(m0 + r0)      * K + e0;
  const u16* a1 = A  + (size_t)(m0 + r0 + 64) * K + e0;
  const u16* b0 = Bw + (size_t)(n0 + r0)      * K + e0;
  const u16* b1 = Bw + (size_t)(n0 + r0 + 64) * K + e0;
  // wave-uniform LDS destination bases (HW adds lane*16 bytes)
  u16* as0 = As + wave * 512;          // byte offset wave*1024
  u16* as1 = As + 2048 + wave * 512;   // + 4096 B
  u16* bs0 = Bs + wave * 512;
  u16* bs1 = Bs + 2048 + wave * 512;

  f32x4 acc[4][4];
  const f32x4 fz = {0.f, 0.f, 0.f, 0.f};
#pragma unroll
  for (int i = 0; i < 4; ++i)
#pragma unroll
    for (int j = 0; j < 4; ++j) acc[i][j] = fz;

  for (int k0 = 0; k0 < K; k0 += 32) {
    __syncthreads();                 // prior iteration's LDS reads complete
    GLOAD16(a0 + k0, as0);
    GLOAD16(a1 + k0, as1);
    GLOAD16(b0 + k0, bs0);
    GLOAD16(b1 + k0, bs1);
    __syncthreads();                 // vmcnt(0) drained before barrier: data in LDS
    bf16x8 af[4], bfr[4];
#pragma unroll
    for (int mt = 0; mt < 4; ++mt)
      af[mt] = *(const bf16x8*)&As[(wr * 64 + mt * 16 + l16) * 32 + quad * 8];
#pragma unroll
    for (int nt = 0; nt < 4; ++nt)
      bfr[nt] = *(const bf16x8*)&Bs[(wc * 64 + nt * 16 + l16) * 32 + quad * 8];
#pragma unroll
    for (int mt = 0; mt < 4; ++mt)
#pragma unroll
      for (int nt = 0; nt < 4; ++nt)
        acc[mt][nt] = __builtin_amdgcn_mfma_f32_16x16x32_bf16(af[mt], bfr[nt],
                                                              acc[mt][nt], 0, 0, 0);
  }
#pragma unroll
  for (int mt = 0; mt < 4; ++mt)
#pragma unroll
    for (int nt = 0; nt < 4; ++nt) {
      int row = m0 + wr * 64 + mt * 16 + quad * 4;
      int col = n0 + wc * 64 + nt * 16 + l16;
      if (OUTF32) {
        float* cp = (float*)C + (size_t)row * N + col;
#pragma unroll
        for (int r = 0; r < 4; ++r)
          cp[(size_t)r * N] = acc[mt][nt][r];
      } else {
        u16* cp = (u16*)C + (size_t)row * N + col;
#pragma unroll
        for (int r = 0; r < 4; ++r)
          cp[(size_t)r * N] = f2bf(acc[mt][nt][r]);
      }
    }
}

// ---------------------------------------------------------------------------
// In-place RoPE on Q (B,S,NH,HD) and K (B,S,NKV,HD), both bf16;
// freqs_cos/sin are float32, batch stride passed from host. One thread/pair.
// ---------------------------------------------------------------------------
__global__ __launch_bounds__(256) void rope_k(u16* __restrict__ Q, u16* __restrict__ Kr,
                                              const float* __restrict__ fc,
                                              const float* __restrict__ fs,
                                              u32 f_bstride) {
  const u32 NQ = (u32)B_ * S_ * NH_ * (HD_ / 2);   // 2^23
  u32 gid = blockIdx.x * 256u + threadIdx.x;
  u16* p;
  u32 b, s, i;
  if (gid < NQ) {
    i = gid & 63u;
    u32 h = (gid >> 6) & 31u;
    s = (gid >> 11) & 2047u;
    b = gid >> 22;
    p = Q + ((size_t)(b * S_ + s) * (NH_ * HD_) + h * HD_ + i * 2);
  } else {
    u32 g = gid - NQ;
    i = g & 63u;
    u32 h = (g >> 6) & 7u;
    s = (g >> 9) & 2047u;
    b = g >> 20;
    p = Kr + ((size_t)(b * S_ + s) * (NKV_ * HD_) + h * HD_ + i * 2);
  }
  u32 xx = *(const u32*)p;
  float x0 = bf2f((u16)(xx & 0xffffu));
  float x1 = bf2f((u16)(xx >> 16));
  u32 fidx = b * f_bstride + s * (HD_ / 2) + i;
  float c  = fc[fidx];
  float sn = fs[fidx];
  float o0 = x0 * c - x1 * sn;
  float o1 = x0 * sn + x1 * c;
  *(u32*)p = (u32)f2bf(o0) | ((u32)f2bf(o1) << 16);
}

// ---------------------------------------------------------------------------
// Flash attention, causal, GQA 4:1. One block per (64-row q-tile, head, batch).
// (unchanged this round — bank-conflict/structure rework planned separately)
// ---------------------------------------------------------------------------
__global__ __launch_bounds__(256) void attn_k(const u16* Q,
                                              const u16* __restrict__ Kr,
                                              const u16* __restrict__ V,
                                              u16* O) {
  __shared__ u16 Ks[64 * 136];   // [kv 0..63][d 0..127], stride 136 (272 B = 17*16)
  __shared__ u16 Vs[128 * 72];   // [d 0..127][kv 0..63], stride 72  (144 B = 9*16)
  __shared__ u16 Ps[64 * 72];    // [q 0..63][kv 0..63],  stride 72
  const int tid  = threadIdx.x;
  const int wave = tid >> 6;
  const int lane = tid & 63;
  const int quad = lane >> 4;
  const int l16  = lane & 15;
  const int qt = blockIdx.x;
  const int h  = blockIdx.y;
  const int b  = blockIdx.z;
  const int kvh = h >> 2;
  const int q0  = qt * 64;

  const u16* Qb = Q  + (size_t)b * S_ * (NH_ * HD_)  + (size_t)h * HD_;
  const u16* Kb = Kr + (size_t)b * S_ * (NKV_ * HD_) + (size_t)kvh * HD_;
  const u16* Vb = V  + (size_t)b * S_ * (NKV_ * HD_) + (size_t)kvh * HD_;

  // Q fragments for this wave's 16-row strip (A-operand layout)
  bf16x8 qf[4];
  {
    const u16* qrow = Qb + (size_t)(q0 + wave * 16 + l16) * (NH_ * HD_);
#pragma unroll
    for (int ks = 0; ks < 4; ++ks)
      qf[ks] = *(const bf16x8*)&qrow[ks * 32 + quad * 8];
  }

  float m_run[4] = {M_INIT, M_INIT, M_INIT, M_INIT};
  float l_run[4] = {0.f, 0.f, 0.f, 0.f};
  f32x4 o_acc[8];
  const f32x4 fz = {0.f, 0.f, 0.f, 0.f};
#pragma unroll
  for (int dt = 0; dt < 8; ++dt) o_acc[dt] = fz;

  const int lr = tid >> 4;          // 0..15
  const int lc = (tid & 15) << 3;   // 0..120

  for (int j = 0; j <= qt; ++j) {
    __syncthreads();   // previous iteration's LDS reads complete
    // stage K tile and transposed V tile
#pragma unroll
    for (int p = 0; p < 4; ++p) {
      int row = p * 16 + lr;
      size_t goff = (size_t)(j * 64 + row) * (NKV_ * HD_) + lc;
      int4 kv4 = *(const int4*)(Kb + goff);
      int4 vv4 = *(const int4*)(Vb + goff);
      *(int4*)&Ks[row * 136 + lc] = kv4;
      u16* vp = (u16*)&vv4;
#pragma unroll
      for (int i = 0; i < 8; ++i) Vs[(lc + i) * 72 + row] = vp[i];
    }
    __syncthreads();

    // S = (Q K^T) * scale for this wave's 16x64 strip
    f32x4 s[4];
#pragma unroll
    for (int nt = 0; nt < 4; ++nt) {
      f32x4 a = fz;
#pragma unroll
      for (int ks = 0; ks < 4; ++ks) {
        bf16x8 kf = *(const bf16x8*)&Ks[(nt * 16 + l16) * 136 + ks * 32 + quad * 8];
        a = __builtin_amdgcn_mfma_f32_16x16x32_bf16(qf[ks], kf, a, 0, 0, 0);
      }
#pragma unroll
      for (int r = 0; r < 4; ++r) a[r] *= SCALE;
      s[nt] = a;
    }
    if (j == qt) {   // diagonal tile: causal mask
#pragma unroll
      for (int nt = 0; nt < 4; ++nt)
#pragma unroll
        for (int r = 0; r < 4; ++r) {
          int col = nt * 16 + l16;
          int rw  = wave * 16 + quad * 4 + r;
          if (col > rw) s[nt][r] = MASK_NEG;
        }
    }

    // online softmax (rows live in 16-lane quads; reduce with xor shuffles)
    float alpha[4], mnew[4];
#pragma unroll
    for (int r = 0; r < 4; ++r) {
      float v = fmaxf(fmaxf(s[0][r], s[1][r]), fmaxf(s[2][r], s[3][r]));
      v = fmaxf(v, __shfl_xor(v, 1));
      v = fmaxf(v, __shfl_xor(v, 2));
      v = fmaxf(v, __shfl_xor(v, 4));
      v = fmaxf(v, __shfl_xor(v, 8));
      mnew[r]  = fmaxf(m_run[r], v);
      alpha[r] = __expf(m_run[r] - mnew[r]);   // first iter: exp(-1e30)=0, finite path
      m_run[r] = mnew[r];
    }
    float rs[4] = {0.f, 0.f, 0.f, 0.f};
#pragma unroll
    for (int nt = 0; nt < 4; ++nt)
#pragma unroll
      for (int r = 0; r < 4; ++r) {
        float pv = __expf(s[nt][r] - mnew[r]);
        rs[r] += pv;
        Ps[(wave * 16 + quad * 4 + r) * 72 + nt * 16 + l16] = f2bf(pv);
      }
#pragma unroll
    for (int r = 0; r < 4; ++r) {
      float v = rs[r];
      v += __shfl_xor(v, 1);
      v += __shfl_xor(v, 2);
      v += __shfl_xor(v, 4);
      v += __shfl_xor(v, 8);
      l_run[r] = l_run[r] * alpha[r] + v;
    }
#pragma unroll
    for (int dt = 0; dt < 8; ++dt)
#pragma unroll
      for (int r = 0; r < 4; ++r) o_acc[dt][r] *= alpha[r];
    __syncthreads();   // P visible (also orders vs. other waves before restage)

    // O += P V  (P as A-operand from LDS, V^T as B-operand from LDS)
#pragma unroll
    for (int ks2 = 0; ks2 < 2; ++ks2) {
      bf16x8 pf = *(const bf16x8*)&Ps[(wave * 16 + l16) * 72 + ks2 * 32 + quad * 8];
#pragma unroll
      for (int dt = 0; dt < 8; ++dt) {
        bf16x8 vf = *(const bf16x8*)&Vs[(dt * 16 + l16) * 72 + ks2 * 32 + quad * 8];
        o_acc[dt] = __builtin_amdgcn_mfma_f32_16x16x32_bf16(pf, vf, o_acc[dt], 0, 0, 0);
      }
    }
  }

  // epilogue: O / l, write (B,S,NH*HD) — same slab this block's Q came from
#pragma unroll
  for (int r = 0; r < 4; ++r) {
    float inv = 1.f / l_run[r];
    int srow = q0 + wave * 16 + quad * 4 + r;
    u16* op = O + (size_t)(b * S_ + srow) * (NH_ * HD_) + h * HD_ + l16;
#pragma unroll
    for (int dt = 0; dt < 8; ++dt)
      op[dt * 16] = f2bf(o_acc[dt][r] * inv);
  }
}

// ---------------------------------------------------------------------------
// Dtype contract: all 7 inputs float32; OUTPUT float32.
// Primary path (needs 117.4 MB ws):
//   ws: Qraw 33.5MB | Kraw 8.4MB | Vraw 8.4MB | Xbf 33.5MB | Wbf 33.5MB
//   cvt x->Xbf; per-GEMM cvt weight->Wbf (Wbf reused serially, same stream);
//   gemm_lds uses global_load_lds width=16 staging (m97 structure).
// Fallback path (small ws): previous inline-convert gemm_bt sequence.
// Attention output overwrites Qraw in place (block-disjoint slabs).
// ---------------------------------------------------------------------------
extern "C" void kernel_launch(void* const* d_in, const int* in_sizes, int n_in,
                              void* d_out, int out_size, void* d_ws, size_t ws_size,
                              hipStream_t stream) {
  (void)n_in; (void)out_size;
  const void*  x  = d_in[0];                 // (B*S, 4096) fp32
  const float* fc = (const float*)d_in[1];   // (B, S, 64)  fp32 (or (S,64))
  const float* fs = (const float*)d_in[2];
  const void*  wq = d_in[3];                 // (4096, 4096) fp32
  const void*  wk = d_in[4];                 // (1024, 4096) fp32
  const void*  wv = d_in[5];                 // (1024, 4096) fp32
  const void*  wo = d_in[6];                 // (4096, 4096) fp32

  u16* Qraw = (u16*)d_ws;                               // (B*S, 4096) bf16
  u16* Kraw = Qraw + (size_t)B_ * S_ * NH_ * HD_;       // (B*S, 1024) bf16
  u16* Vraw = Kraw + (size_t)B_ * S_ * NKV_ * HD_;      // (B*S, 1024) bf16

  // freqs batch stride: 0 if stored (S,64) shared across batch, else S*64
  u32 f_bstride = (in_sizes[1] >= (int)(B_ * S_ * (HD_ / 2))) ? (u32)(S_ * (HD_ / 2)) : 0u;

  const size_t elems_x = (size_t)B_ * S_ * H_;          // 16,777,216
  const size_t need = ((size_t)B_ * S_ * (NH_ + 2 * NKV_) * HD_ + 2 * elems_x) * 2;

  if (ws_size >= need) {
    u16* Xbf = Vraw + (size_t)B_ * S_ * NKV_ * HD_;
    u16* Wbf = Xbf + elems_x;
    // x -> bf16 (4,194,304 float4 chunks)
    cvt_bf16<<<16384, 256, 0, stream>>>((const float*)x, Xbf, 4194304u);
    // Q = x @ wq^T
    cvt_bf16<<<16384, 256, 0, stream>>>((const float*)wq, Wbf, 4194304u);
    gemm_lds<0><<<dim3(32, 32), 256, 0, stream>>>(Xbf, Wbf, Qraw, 4096, 4096, 4096);
    // K = x @ wk^T
    cvt_bf16<<<4096, 256, 0, stream>>>((const float*)wk, Wbf, 1048576u);
    gemm_lds<0><<<dim3(8, 32), 256, 0, stream>>>(Xbf, Wbf, Kraw, 4096, 1024, 4096);
    // V = x @ wv^T
    cvt_bf16<<<4096, 256, 0, stream>>>((const float*)wv, Wbf, 1048576u);
    gemm_lds<0><<<dim3(8, 32), 256, 0, stream>>>(Xbf, Wbf, Vraw, 4096, 1024, 4096);
    rope_k<<<40960, 256, 0, stream>>>(Qraw, Kraw, fc, fs, f_bstride);
    attn_k<<<dim3(32, 32, 2), 256, 0, stream>>>(Qraw, Kraw, Vraw, /*O in-place*/ Qraw);
    // out = O @ wo^T (fp32 out)
    cvt_bf16<<<16384, 256, 0, stream>>>((const float*)wo, Wbf, 4194304u);
    gemm_lds<1><<<dim3(32, 32), 256, 0, stream>>>(Qraw, Wbf, d_out, 4096, 4096, 4096);
  } else {
    gemm_bt<1, 1, 0><<<dim3(32, 32), 256, 0, stream>>>(x, wq, Qraw, 4096, 4096, 4096);
    gemm_bt<1, 1, 0><<<dim3(8, 32),  256, 0, stream>>>(x, wk, Kraw, 4096, 1024, 4096);
    gemm_bt<1, 1, 0><<<dim3(8, 32),  256, 0, stream>>>(x, wv, Vraw, 4096, 1024, 4096);
    rope_k<<<40960, 256, 0, stream>>>(Qraw, Kraw, fc, fs, f_bstride);
    attn_k<<<dim3(32, 32, 2), 256, 0, stream>>>(Qraw, Kraw, Vraw, Qraw);
    gemm_bt<0, 1, 1><<<dim3(32, 32), 256, 0, stream>>>(Qraw, wo, d_out, 4096, 4096, 4096);
  }
}

// Round 4
// 1347.360 us; speedup vs baseline: 1.3760x; 1.1121x over previous
//
#include <hip/hip_runtime.h>
#include <math.h>

typedef unsigned short u16;
typedef unsigned int u32;
typedef __bf16 bf16x8 __attribute__((ext_vector_type(8)));
typedef float f32x4 __attribute__((ext_vector_type(4)));
typedef unsigned int u32x2 __attribute__((ext_vector_type(2)));

#define B_ 2
#define S_ 2048
#define H_ 4096
#define NH_ 32
#define NKV_ 8
#define HD_ 128
#define SCALE 0.08838834764831845f
#define MASK_NEG -30000.0f   // exp(-30000 - m) flushes to exactly 0.0f, same as np ref
#define M_INIT  -1.0e30f     // finite "minus infinity": exp(-1e30 - m) == 0.0f, no inf math

static __device__ __forceinline__ u16 f2bf(float f) {
  union { float f; u32 u; } v; v.f = f;
  u32 u = v.u;
  u += ((u >> 16) & 1u) + 0x7FFFu;   // round-to-nearest-even
  return (u16)(u >> 16);
}
static __device__ __forceinline__ float bf2f(u16 h) {
  union { u32 u; float f; } v; v.u = ((u32)h) << 16;
  return v.f;
}

// Load 8 contiguous elements starting at element offset `off`.
// F32 != 0: source is float32, convert to 8 bf16 (RTNE).  F32 == 0: source bf16.
template<int F32>
static __device__ __forceinline__ int4 ld8(const void* __restrict__ base, size_t off) {
  if (F32) {
    const float* p = (const float*)base + off;
    const float4 x0 = *(const float4*)p;
    const float4 x1 = *(const float4*)(p + 4);
    union { u16 h[8]; int4 v; } u;
    u.h[0] = f2bf(x0.x); u.h[1] = f2bf(x0.y); u.h[2] = f2bf(x0.z); u.h[3] = f2bf(x0.w);
    u.h[4] = f2bf(x1.x); u.h[5] = f2bf(x1.y); u.h[6] = f2bf(x1.z); u.h[7] = f2bf(x1.w);
    return u.v;
  }
  return *(const int4*)((const u16*)base + off);
}

// ---------------------------------------------------------------------------
// FALLBACK GEMM (only used if workspace is too small for the bf16 scratch):
// C[m][n] = sum_k A[m][k] * Bw[n][k], fp32->bf16 inline during LDS staging.
// ---------------------------------------------------------------------------
#define BK 32
#define LDA 40   // padded LDS stride for fallback path

template<int AF32, int BF32, int OUTF32>
__global__ __launch_bounds__(256) void gemm_bt(const void* __restrict__ A,
                                               const void* __restrict__ Bw,
                                               void* __restrict__ C,
                                               int M, int N, int K) {
  __shared__ u16 As[128 * LDA];
  __shared__ u16 Bs[128 * LDA];
  const int tid  = threadIdx.x;
  const int wave = tid >> 6;
  const int lane = tid & 63;
  const int quad = lane >> 4;
  const int l16  = lane & 15;
  const int wr = wave >> 1, wc = wave & 1;
  const int m0 = blockIdx.y * 128, n0 = blockIdx.x * 128;
  const int srow = tid >> 2;          // 0..63
  const int scol = (tid & 3) << 3;    // 0,8,16,24

  f32x4 acc[4][4];
  const f32x4 fz = {0.f, 0.f, 0.f, 0.f};
  for (int i = 0; i < 4; ++i)
    for (int j = 0; j < 4; ++j) acc[i][j] = fz;

  const size_t ao0 = (size_t)(m0 + srow)      * K + scol;
  const size_t ao1 = (size_t)(m0 + srow + 64) * K + scol;
  const size_t bo0 = (size_t)(n0 + srow)      * K + scol;
  const size_t bo1 = (size_t)(n0 + srow + 64) * K + scol;

  for (int k0 = 0; k0 < K; k0 += BK) {
    int4 a0 = ld8<AF32>(A,  ao0 + k0);
    int4 a1 = ld8<AF32>(A,  ao1 + k0);
    int4 b0 = ld8<BF32>(Bw, bo0 + k0);
    int4 b1 = ld8<BF32>(Bw, bo1 + k0);
    __syncthreads();
    *(int4*)&As[srow * LDA + scol]        = a0;
    *(int4*)&As[(srow + 64) * LDA + scol] = a1;
    *(int4*)&Bs[srow * LDA + scol]        = b0;
    *(int4*)&Bs[(srow + 64) * LDA + scol] = b1;
    __syncthreads();
    bf16x8 af[4], bfr[4];
#pragma unroll
    for (int mt = 0; mt < 4; ++mt)
      af[mt] = *(const bf16x8*)&As[(wr * 64 + mt * 16 + l16) * LDA + quad * 8];
#pragma unroll
    for (int nt = 0; nt < 4; ++nt)
      bfr[nt] = *(const bf16x8*)&Bs[(wc * 64 + nt * 16 + l16) * LDA + quad * 8];
#pragma unroll
    for (int mt = 0; mt < 4; ++mt)
#pragma unroll
      for (int nt = 0; nt < 4; ++nt)
        acc[mt][nt] = __builtin_amdgcn_mfma_f32_16x16x32_bf16(af[mt], bfr[nt],
                                                              acc[mt][nt], 0, 0, 0);
  }
#pragma unroll
  for (int mt = 0; mt < 4; ++mt)
#pragma unroll
    for (int nt = 0; nt < 4; ++nt) {
      int row = m0 + wr * 64 + mt * 16 + quad * 4;
      int col = n0 + wc * 64 + nt * 16 + l16;
      if (OUTF32) {
        float* cp = (float*)C + (size_t)row * N + col;
#pragma unroll
        for (int r = 0; r < 4; ++r)
          cp[(size_t)r * N] = acc[mt][nt][r];
      } else {
        u16* cp = (u16*)C + (size_t)row * N + col;
#pragma unroll
        for (int r = 0; r < 4; ++r)
          cp[(size_t)r * N] = f2bf(acc[mt][nt][r]);
      }
    }
}

// ---------------------------------------------------------------------------
// fp32 -> bf16 (RTNE) elementwise. n4 = n_elems / 4.
// ---------------------------------------------------------------------------
__global__ __launch_bounds__(256) void cvt_bf16(const float* __restrict__ in,
                                                u16* __restrict__ out, u32 n4) {
  u32 i = blockIdx.x * 256u + threadIdx.x;
  if (i >= n4) return;
  const float4 x = ((const float4*)in)[i];
  u32 lo = (u32)f2bf(x.x) | ((u32)f2bf(x.y) << 16);
  u32 hi = (u32)f2bf(x.z) | ((u32)f2bf(x.w) << 16);
  ((uint2*)out)[i] = make_uint2(lo, hi);
}

// ---------------------------------------------------------------------------
// PRIMARY GEMM (m97 structure): both operands bf16 K-major, staged via
// global_load_lds width=16 into linear LDS. 128x128 tile, BK=32, 4 waves.
// ---------------------------------------------------------------------------
#define GLOAD16(gp, lp)                                            \
  __builtin_amdgcn_global_load_lds(                                \
      (__attribute__((address_space(1))) void*)(gp),               \
      (__attribute__((address_space(3))) void*)(lp), 16, 0, 0)

template<int OUTF32>
__global__ __launch_bounds__(256) void gemm_lds(const u16* __restrict__ A,
                                                const u16* __restrict__ Bw,
                                                void* __restrict__ C,
                                                int M, int N, int K) {
  __shared__ u16 As[128 * 32];
  __shared__ u16 Bs[128 * 32];
  const int tid  = threadIdx.x;
  const int wave = tid >> 6;
  const int lane = tid & 63;
  const int quad = lane >> 4;
  const int l16  = lane & 15;
  const int wr = wave >> 1, wc = wave & 1;
  const int m0 = blockIdx.y * 128, n0 = blockIdx.x * 128;

  const int r0 = tid >> 2;            // 0..63
  const int e0 = (tid & 3) << 3;      // 0,8,16,24
  const u16* a0 = A  + (size_t)(m0 + r0)      * K + e0;
  const u16* a1 = A  + (size_t)(m0 + r0 + 64) * K + e0;
  const u16* b0 = Bw + (size_t)(n0 + r0)      * K + e0;
  const u16* b1 = Bw + (size_t)(n0 + r0 + 64) * K + e0;
  u16* as0 = As + wave * 512;
  u16* as1 = As + 2048 + wave * 512;
  u16* bs0 = Bs + wave * 512;
  u16* bs1 = Bs + 2048 + wave * 512;

  f32x4 acc[4][4];
  const f32x4 fz = {0.f, 0.f, 0.f, 0.f};
#pragma unroll
  for (int i = 0; i < 4; ++i)
#pragma unroll
    for (int j = 0; j < 4; ++j) acc[i][j] = fz;

  for (int k0 = 0; k0 < K; k0 += 32) {
    __syncthreads();
    GLOAD16(a0 + k0, as0);
    GLOAD16(a1 + k0, as1);
    GLOAD16(b0 + k0, bs0);
    GLOAD16(b1 + k0, bs1);
    __syncthreads();
    bf16x8 af[4], bfr[4];
#pragma unroll
    for (int mt = 0; mt < 4; ++mt)
      af[mt] = *(const bf16x8*)&As[(wr * 64 + mt * 16 + l16) * 32 + quad * 8];
#pragma unroll
    for (int nt = 0; nt < 4; ++nt)
      bfr[nt] = *(const bf16x8*)&Bs[(wc * 64 + nt * 16 + l16) * 32 + quad * 8];
#pragma unroll
    for (int mt = 0; mt < 4; ++mt)
#pragma unroll
      for (int nt = 0; nt < 4; ++nt)
        acc[mt][nt] = __builtin_amdgcn_mfma_f32_16x16x32_bf16(af[mt], bfr[nt],
                                                              acc[mt][nt], 0, 0, 0);
  }
#pragma unroll
  for (int mt = 0; mt < 4; ++mt)
#pragma unroll
    for (int nt = 0; nt < 4; ++nt) {
      int row = m0 + wr * 64 + mt * 16 + quad * 4;
      int col = n0 + wc * 64 + nt * 16 + l16;
      if (OUTF32) {
        float* cp = (float*)C + (size_t)row * N + col;
#pragma unroll
        for (int r = 0; r < 4; ++r)
          cp[(size_t)r * N] = acc[mt][nt][r];
      } else {
        u16* cp = (u16*)C + (size_t)row * N + col;
#pragma unroll
        for (int r = 0; r < 4; ++r)
          cp[(size_t)r * N] = f2bf(acc[mt][nt][r]);
      }
    }
}

// ---------------------------------------------------------------------------
// In-place RoPE (unchanged).
// ---------------------------------------------------------------------------
__global__ __launch_bounds__(256) void rope_k(u16* __restrict__ Q, u16* __restrict__ Kr,
                                              const float* __restrict__ fc,
                                              const float* __restrict__ fs,
                                              u32 f_bstride) {
  const u32 NQ = (u32)B_ * S_ * NH_ * (HD_ / 2);   // 2^23
  u32 gid = blockIdx.x * 256u + threadIdx.x;
  u16* p;
  u32 b, s, i;
  if (gid < NQ) {
    i = gid & 63u;
    u32 h = (gid >> 6) & 31u;
    s = (gid >> 11) & 2047u;
    b = gid >> 22;
    p = Q + ((size_t)(b * S_ + s) * (NH_ * HD_) + h * HD_ + i * 2);
  } else {
    u32 g = gid - NQ;
    i = g & 63u;
    u32 h = (g >> 6) & 7u;
    s = (g >> 9) & 2047u;
    b = g >> 20;
    p = Kr + ((size_t)(b * S_ + s) * (NKV_ * HD_) + h * HD_ + i * 2);
  }
  u32 xx = *(const u32*)p;
  float x0 = bf2f((u16)(xx & 0xffffu));
  float x1 = bf2f((u16)(xx >> 16));
  u32 fidx = b * f_bstride + s * (HD_ / 2) + i;
  float c  = fc[fidx];
  float sn = fs[fidx];
  float o0 = x0 * c - x1 * sn;
  float o1 = x0 * sn + x1 * c;
  *(u32*)p = (u32)f2bf(o0) | ((u32)f2bf(o1) << 16);
}

// ---------------------------------------------------------------------------
// Hardware transpose read (m156/m162 semantics, reconciled):
//   per-lane byte address A; subtile = the 128B-aligned block containing A;
//   column c = (A mod 128)/8  (8 BYTES per column step);
//   elem j returns the bf16 at block_base + c*2 + j*32  (row j of column c
//   of the [4][16] bf16 row-major subtile).
// offset:N immediate is additive bytes.
// So: to read column l16, supply base + l16*8 bytes (= u16 index l16*4).
// ---------------------------------------------------------------------------
template<int IMM>
static __device__ __forceinline__ u32x2 trread(const u16* p) {
  u32x2 d;
  asm volatile("ds_read_b64_tr_b16 %0, %1 offset:%2"
               : "=v"(d)
               : "v"((__attribute__((address_space(3))) const u16*)p), "n"(IMM));
  return d;
}

// ---------------------------------------------------------------------------
// Flash attention, causal, GQA 4:1. One block per (64-row q-tile, head, batch).
// 4 waves; wave w owns q rows [w*16, w*16+16).
//
// v4 = v3 with the tr-read base reverted to R2's (correct) form:
//   vb = &Vsub[quad*1024 + l16*4]  -> byte quad*2048 + l16*8 = column l16.
//   (v3's l16*2-byte base read column l16/4 — scrambled V.)
// Keeps v3's fixes: Ps rows carry wave offset (no inter-wave race); compiler
// memory fence between P uint2-stores and P bf16x8-loads.
// Structure:
//  - swapped QK^T: s = mfma(K_frag, Q_frag) -> C[kv][q], q = l16 lane-local;
//    softmax reduce = 2 shfl_xor; P staged as 4 packed b64 stores.
//  - V staged in subtiled [kv/4][d/16][4][16] layout, b128 writes; PV
//    B-fragments via ds_read_b64_tr_b16 (T10).
//  - 2 barriers/tile; T14 prefetch of next K/V tile; T5 setprio around MFMA.
// ---------------------------------------------------------------------------
__global__ __launch_bounds__(256, 3) void attn_k(const u16* Q,
                                                 const u16* __restrict__ Kr,
                                                 const u16* __restrict__ V,
                                                 u16* O) {
  __shared__ u16 Ks[64 * 136];   // [kv 0..63][d 0..127], stride 136
  __shared__ u16 Vsub[8192];     // [kb=kv/4][db=d/16][kv%4][d%16]
  __shared__ u16 Ps[64 * 72];    // [q 0..63][kv 0..63], stride 72
  const int tid  = threadIdx.x;
  const int wave = tid >> 6;
  const int lane = tid & 63;
  const int quad = lane >> 4;
  const int l16  = lane & 15;
  const int qt = blockIdx.x;
  const int h  = blockIdx.y;
  const int b  = blockIdx.z;
  const int kvh = h >> 2;
  const int q0  = qt * 64;

  const u16* Qb = Q  + (size_t)b * S_ * (NH_ * HD_)  + (size_t)h * HD_;
  const u16* Kb = Kr + (size_t)b * S_ * (NKV_ * HD_) + (size_t)kvh * HD_;
  const u16* Vb = V  + (size_t)b * S_ * (NKV_ * HD_) + (size_t)kvh * HD_;

  // Q fragments: lane l16 = q row (B-operand of swapped QK^T)
  bf16x8 qf[4];
  {
    const u16* qrow = Qb + (size_t)(q0 + wave * 16 + l16) * (NH_ * HD_);
#pragma unroll
    for (int ks = 0; ks < 4; ++ks)
      qf[ks] = *(const bf16x8*)&qrow[ks * 32 + quad * 8];
  }

  float m_run = M_INIT;   // running max for q = q0 + wave*16 + l16 (quad-replicated)
  float l_run = 0.f;
  f32x4 o_acc[8];
  const f32x4 fz = {0.f, 0.f, 0.f, 0.f};
#pragma unroll
  for (int dt = 0; dt < 8; ++dt) o_acc[dt] = fz;

  const int lr = tid >> 4;          // 0..15 (block-wide stage row helper)
  const int lc = (tid & 15) << 3;   // 0..120
  // per-lane tr-read base: column l16 => byte l16*8 (u16 index l16*4);
  // quad selects kv-subgroup: quad*2048 B = 2 kb blocks => kv base quad*8
  const u16* vb = &Vsub[quad * 1024 + l16 * 4];

  // prefetch tile 0 into registers (T14)
  int4 kreg[4], vreg[4];
#pragma unroll
  for (int p = 0; p < 4; ++p) {
    size_t g = (size_t)(p * 16 + lr) * (NKV_ * HD_) + lc;
    kreg[p] = *(const int4*)(Kb + g);
    vreg[p] = *(const int4*)(Vb + g);
  }

  for (int j = 0; j <= qt; ++j) {
    __syncthreads();   // previous iteration's LDS reads complete
    // stage K (row-major, stride 136) and V (subtiled) from registers
#pragma unroll
    for (int p = 0; p < 4; ++p) {
      int kv = p * 16 + lr;
      *(int4*)&Ks[kv * 136 + lc] = kreg[p];
      *(int4*)&Vsub[((kv >> 2) * 8 + (lc >> 4)) * 64 + (kv & 3) * 16 + (lc & 8)] = vreg[p];
    }
    __syncthreads();   // staged tile visible
    if (j < qt) {      // issue next tile's loads; latency hides under compute
#pragma unroll
      for (int p = 0; p < 4; ++p) {
        size_t g = (size_t)((j + 1) * 64 + p * 16 + lr) * (NKV_ * HD_) + lc;
        kreg[p] = *(const int4*)(Kb + g);
        vreg[p] = *(const int4*)(Vb + g);
      }
    }

    // S^T = (K Q^T) * scale : C[kv][q]; lane: q = l16, kv = nt*16 + quad*4 + r
    f32x4 s[4];
    __builtin_amdgcn_s_setprio(1);
#pragma unroll
    for (int nt = 0; nt < 4; ++nt) {
      f32x4 a = fz;
#pragma unroll
      for (int ks = 0; ks < 4; ++ks) {
        bf16x8 kf = *(const bf16x8*)&Ks[(nt * 16 + l16) * 136 + ks * 32 + quad * 8];
        a = __builtin_amdgcn_mfma_f32_16x16x32_bf16(kf, qf[ks], a, 0, 0, 0);
      }
#pragma unroll
      for (int r = 0; r < 4; ++r) a[r] *= SCALE;
      s[nt] = a;
    }
    __builtin_amdgcn_s_setprio(0);
    if (j == qt) {   // causal mask: kv_local > q_local
#pragma unroll
      for (int nt = 0; nt < 4; ++nt)
#pragma unroll
        for (int r = 0; r < 4; ++r)
          if (nt * 16 + quad * 4 + r > wave * 16 + l16) s[nt][r] = MASK_NEG;
    }

    // online softmax: lane holds 16 kv-samples of row q = l16; quads hold
    // disjoint kv sets -> reduce across quads with xor 16, 32.
    float pmax;
    {
      float x0 = fmaxf(fmaxf(s[0][0], s[0][1]), fmaxf(s[0][2], s[0][3]));
      float x1 = fmaxf(fmaxf(s[1][0], s[1][1]), fmaxf(s[1][2], s[1][3]));
      float x2 = fmaxf(fmaxf(s[2][0], s[2][1]), fmaxf(s[2][2], s[2][3]));
      float x3 = fmaxf(fmaxf(s[3][0], s[3][1]), fmaxf(s[3][2], s[3][3]));
      pmax = fmaxf(fmaxf(x0, x1), fmaxf(x2, x3));
      pmax = fmaxf(pmax, __shfl_xor(pmax, 16));
      pmax = fmaxf(pmax, __shfl_xor(pmax, 32));
    }
    float mnew  = fmaxf(m_run, pmax);
    float alpha = __expf(m_run - mnew);   // first iter: exp(-1e30)=0, finite path
    m_run = mnew;

    float rs = 0.f;
#pragma unroll
    for (int nt = 0; nt < 4; ++nt) {
      float p0 = __expf(s[nt][0] - mnew);
      float p1 = __expf(s[nt][1] - mnew);
      float p2 = __expf(s[nt][2] - mnew);
      float p3 = __expf(s[nt][3] - mnew);
      rs += (p0 + p1) + (p2 + p3);
      u32 w0 = (u32)f2bf(p0) | ((u32)f2bf(p1) << 16);
      u32 w1 = (u32)f2bf(p2) | ((u32)f2bf(p3) << 16);
      // P[q = wave*16 + l16][kv = nt*16 + quad*4 + 0..3] : wave-private rows
      *(uint2*)&Ps[(wave * 16 + l16) * 72 + nt * 16 + quad * 4] = make_uint2(w0, w1);
    }
    asm volatile("" ::: "memory");   // fence P stores vs. P loads (TBAA)
    rs += __shfl_xor(rs, 16);
    rs += __shfl_xor(rs, 32);
    l_run = l_run * alpha + rs;

    // rescale O: o_acc rows are q = quad*4+r; alpha lives at lane l16 = q
    float a4[4];
#pragma unroll
    for (int r = 0; r < 4; ++r) a4[r] = __shfl(alpha, quad * 4 + r);
#pragma unroll
    for (int dt = 0; dt < 8; ++dt)
#pragma unroll
      for (int r = 0; r < 4; ++r) o_acc[dt][r] *= a4[r];

    // O += P V : A = P rows (wave-private via Ps), B = V^T via tr-reads
#pragma unroll
    for (int ks2 = 0; ks2 < 2; ++ks2) {
      bf16x8 pa = *(const bf16x8*)&Ps[(wave * 16 + l16) * 72 + ks2 * 32 + quad * 8];
      u32x2 t[8][2];
      if (ks2 == 0) {
#pragma unroll
        for (int dt = 0; dt < 8; ++dt) {
          const u16* vp = vb + dt * 64;
          t[dt][0] = trread<0>(vp);       // kv e=0..3 (kb = quad*2)
          t[dt][1] = trread<1024>(vp);    // kv e=4..7 (kb = quad*2 + 1)
        }
      } else {
#pragma unroll
        for (int dt = 0; dt < 8; ++dt) {
          const u16* vp = vb + dt * 64;
          t[dt][0] = trread<8192>(vp);
          t[dt][1] = trread<8192 + 1024>(vp);
        }
      }
      asm volatile("s_waitcnt lgkmcnt(0)" ::: "memory");
      __builtin_amdgcn_sched_barrier(0);
      __builtin_amdgcn_s_setprio(1);
#pragma unroll
      for (int dt = 0; dt < 8; ++dt) {
        union { u32 w[4]; bf16x8 v; } uf;
        uf.w[0] = t[dt][0][0]; uf.w[1] = t[dt][0][1];
        uf.w[2] = t[dt][1][0]; uf.w[3] = t[dt][1][1];
        o_acc[dt] = __builtin_amdgcn_mfma_f32_16x16x32_bf16(pa, uf.v, o_acc[dt], 0, 0, 0);
      }
      __builtin_amdgcn_s_setprio(0);
    }
  }

  // epilogue: O / l, write (B,S,NH*HD) — same slab this block's Q came from
#pragma unroll
  for (int r = 0; r < 4; ++r) {
    float lv  = __shfl(l_run, quad * 4 + r);
    float inv = 1.f / lv;
    int srow = q0 + wave * 16 + quad * 4 + r;
    u16* op = O + (size_t)(b * S_ + srow) * (NH_ * HD_) + h * HD_ + l16;
#pragma unroll
    for (int dt = 0; dt < 8; ++dt)
      op[dt * 16] = f2bf(o_acc[dt][r] * inv);
  }
}

// ---------------------------------------------------------------------------
// Dtype contract: all 7 inputs float32; OUTPUT float32.
// Primary path (needs 117.4 MB ws):
//   ws: Qraw 33.5MB | Kraw 8.4MB | Vraw 8.4MB | Xbf 33.5MB | Wbf 33.5MB
// Fallback path (small ws): inline-convert gemm_bt sequence.
// Attention output overwrites Qraw in place (block-disjoint slabs).
// ---------------------------------------------------------------------------
extern "C" void kernel_launch(void* const* d_in, const int* in_sizes, int n_in,
                              void* d_out, int out_size, void* d_ws, size_t ws_size,
                              hipStream_t stream) {
  (void)n_in; (void)out_size;
  const void*  x  = d_in[0];                 // (B*S, 4096) fp32
  const float* fc = (const float*)d_in[1];   // (B, S, 64)  fp32 (or (S,64))
  const float* fs = (const float*)d_in[2];
  const void*  wq = d_in[3];                 // (4096, 4096) fp32
  const void*  wk = d_in[4];                 // (1024, 4096) fp32
  const void*  wv = d_in[5];                 // (1024, 4096) fp32
  const void*  wo = d_in[6];                 // (4096, 4096) fp32

  u16* Qraw = (u16*)d_ws;                               // (B*S, 4096) bf16
  u16* Kraw = Qraw + (size_t)B_ * S_ * NH_ * HD_;       // (B*S, 1024) bf16
  u16* Vraw = Kraw + (size_t)B_ * S_ * NKV_ * HD_;      // (B*S, 1024) bf16

  u32 f_bstride = (in_sizes[1] >= (int)(B_ * S_ * (HD_ / 2))) ? (u32)(S_ * (HD_ / 2)) : 0u;

  const size_t elems_x = (size_t)B_ * S_ * H_;          // 16,777,216
  const size_t need = ((size_t)B_ * S_ * (NH_ + 2 * NKV_) * HD_ + 2 * elems_x) * 2;

  if (ws_size >= need) {
    u16* Xbf = Vraw + (size_t)B_ * S_ * NKV_ * HD_;
    u16* Wbf = Xbf + elems_x;
    cvt_bf16<<<16384, 256, 0, stream>>>((const float*)x, Xbf, 4194304u);
    cvt_bf16<<<16384, 256, 0, stream>>>((const float*)wq, Wbf, 4194304u);
    gemm_lds<0><<<dim3(32, 32), 256, 0, stream>>>(Xbf, Wbf, Qraw, 4096, 4096, 4096);
    cvt_bf16<<<4096, 256, 0, stream>>>((const float*)wk, Wbf, 1048576u);
    gemm_lds<0><<<dim3(8, 32), 256, 0, stream>>>(Xbf, Wbf, Kraw, 4096, 1024, 4096);
    cvt_bf16<<<4096, 256, 0, stream>>>((const float*)wv, Wbf, 1048576u);
    gemm_lds<0><<<dim3(8, 32), 256, 0, stream>>>(Xbf, Wbf, Vraw, 4096, 1024, 4096);
    rope_k<<<40960, 256, 0, stream>>>(Qraw, Kraw, fc, fs, f_bstride);
    attn_k<<<dim3(32, 32, 2), 256, 0, stream>>>(Qraw, Kraw, Vraw, /*O in-place*/ Qraw);
    cvt_bf16<<<16384, 256, 0, stream>>>((const float*)wo, Wbf, 4194304u);
    gemm_lds<1><<<dim3(32, 32), 256, 0, stream>>>(Qraw, Wbf, d_out, 4096, 4096, 4096);
  } else {
    gemm_bt<1, 1, 0><<<dim3(32, 32), 256, 0, stream>>>(x, wq, Qraw, 4096, 4096, 4096);
    gemm_bt<1, 1, 0><<<dim3(8, 32),  256, 0, stream>>>(x, wk, Kraw, 4096, 1024, 4096);
    gemm_bt<1, 1, 0><<<dim3(8, 32),  256, 0, stream>>>(x, wv, Vraw, 4096, 1024, 4096);
    rope_k<<<40960, 256, 0, stream>>>(Qraw, Kraw, fc, fs, f_bstride);
    attn_k<<<dim3(32, 32, 2), 256, 0, stream>>>(Qraw, Kraw, Vraw, Qraw);
    gemm_bt<0, 1, 1><<<dim3(32, 32), 256, 0, stream>>>(Qraw, wo, d_out, 4096, 4096, 4096);
  }
}